// Round 3
// baseline (2333.133 us; speedup 1.0000x reference)
//
#include <hip/hip_runtime.h>
#include <hip/hip_bf16.h>

typedef __bf16 bf16_t;
typedef __attribute__((ext_vector_type(8))) __bf16 bfrag;   // 8 bf16 = 4 VGPRs (MFMA A/B frag)
typedef __attribute__((ext_vector_type(4))) float f32x4;    // MFMA C/D frag

#define SEQ    4096
#define NDIM   1024
#define NHEAD  16
#define HD     64
#define NBATCH 2
#define MROWS  (NBATCH * SEQ)   // 8192

// ---------------------------------------------------------------------------
// GEMM: C[M,N] = A[M,K] @ W[N,K]^T + bias[N]
// A: fp32 or bf16 (templated), W/bias: fp32, C: fp32 or bf16 (templated).
// fp32 operands are cast to bf16 during LDS staging; accumulate fp32 in MFMA.
// 128x128 tile, BK=32, 256 threads = 4 waves (2x2), each wave 64x64 = 4x4 MFMA.
// C/D layout: col = lane&15, row = quad*4 + reg (verified m89/m91).
// ---------------------------------------------------------------------------
template <typename AT, typename OT>
__global__ __launch_bounds__(256, 2)
void gemm_bt(const AT* __restrict__ A, const float* __restrict__ W,
             const float* __restrict__ bias, OT* __restrict__ C,
             int M, int N, int K)
{
    __shared__ __align__(16) bf16_t As[128 * 32];
    __shared__ __align__(16) bf16_t Bs[128 * 32];

    const int tid  = threadIdx.x;
    const int lane = tid & 63;
    const int wid  = tid >> 6;
    const int n16  = lane & 15;
    const int quad = lane >> 4;
    const int row0 = blockIdx.y * 128;
    const int col0 = blockIdx.x * 128;
    const int wrow = (wid >> 1) * 64;
    const int wcol = (wid & 1) * 64;

    f32x4 acc[4][4];
#pragma unroll
    for (int i = 0; i < 4; i++)
#pragma unroll
        for (int j = 0; j < 4; j++) acc[i][j] = (f32x4){0.f, 0.f, 0.f, 0.f};

    for (int k0 = 0; k0 < K; k0 += 32) {
        // ---- stage A tile (128 x 32) ----
        if constexpr (sizeof(AT) == 4) {
            // fp32 source: float4 loads, convert to bf16
#pragma unroll
            for (int it = 0; it < 4; it++) {
                int idx = tid + it * 256;        // 0..1023
                int r   = idx >> 3;              // 0..127
                int c   = (idx & 7) * 4;         // 0,4,...,28
                float4 v = *(const float4*)(&A[(size_t)(row0 + r) * K + k0 + c]);
                bf16_t* p = &As[r * 32 + c];
                p[0] = (bf16_t)v.x; p[1] = (bf16_t)v.y;
                p[2] = (bf16_t)v.z; p[3] = (bf16_t)v.w;
            }
        } else {
            // bf16 source: straight 16B copies
#pragma unroll
            for (int it = 0; it < 2; it++) {
                int idx = tid + it * 256;        // 0..511
                int r   = idx >> 2;
                int c   = (idx & 3) * 8;
                *(uint4*)(&As[r * 32 + c]) = *(const uint4*)(&A[(size_t)(row0 + r) * K + k0 + c]);
            }
        }
        // ---- stage W tile (128 x 32), always fp32 source ----
#pragma unroll
        for (int it = 0; it < 4; it++) {
            int idx = tid + it * 256;
            int r   = idx >> 3;
            int c   = (idx & 7) * 4;
            float4 v = *(const float4*)(&W[(size_t)(col0 + r) * K + k0 + c]);
            bf16_t* p = &Bs[r * 32 + c];
            p[0] = (bf16_t)v.x; p[1] = (bf16_t)v.y;
            p[2] = (bf16_t)v.z; p[3] = (bf16_t)v.w;
        }
        __syncthreads();

        bfrag af[4], bfg[4];
#pragma unroll
        for (int i = 0; i < 4; i++)
            af[i] = *(const bfrag*)(&As[(wrow + i * 16 + n16) * 32 + quad * 8]);
#pragma unroll
        for (int j = 0; j < 4; j++)
            bfg[j] = *(const bfrag*)(&Bs[(wcol + j * 16 + n16) * 32 + quad * 8]);

#pragma unroll
        for (int i = 0; i < 4; i++)
#pragma unroll
            for (int j = 0; j < 4; j++)
                acc[i][j] = __builtin_amdgcn_mfma_f32_16x16x32_bf16(af[i], bfg[j], acc[i][j], 0, 0, 0);
        __syncthreads();
    }

    // ---- epilogue: add bias (fp32), store ----
#pragma unroll
    for (int i = 0; i < 4; i++) {
#pragma unroll
        for (int j = 0; j < 4; j++) {
#pragma unroll
            for (int r = 0; r < 4; r++) {
                int row = row0 + wrow + i * 16 + quad * 4 + r;
                int col = col0 + wcol + j * 16 + n16;
                float v = acc[i][j][r] + bias[col];
                C[(size_t)row * N + col] = (OT)v;
            }
        }
    }
}

// ---------------------------------------------------------------------------
// Naive sliding-window attention (correctness baseline).
// One wave per query; 4 waves per block. fp32 math; Q/K/V/out bf16 buffers.
// Query q attends keys ka in [q-511, q] ∩ [0,S).
// ---------------------------------------------------------------------------
__global__ __launch_bounds__(256, 2)
void attn_naive(const bf16_t* __restrict__ Q, const bf16_t* __restrict__ Kg,
                const bf16_t* __restrict__ Vg, bf16_t* __restrict__ AO)
{
    __shared__ float Qrow[4][64];
    __shared__ float Prow[4][512];

    const int tid  = threadIdx.x;
    const int wid  = tid >> 6;
    const int lane = tid & 63;

    const int q  = blockIdx.x * 4 + wid;
    const int bh = blockIdx.y;
    const int b  = bh >> 4;
    const int h  = bh & 15;
    const size_t base = (size_t)b * SEQ * NDIM + (size_t)h * HD;

    Qrow[wid][lane] = (float)Q[base + (size_t)q * NDIM + lane];
    __syncthreads();

    const int lo = q - 511;

    float sc[8];
#pragma unroll
    for (int i = 0; i < 8; i++) {
        int ka = lo + i * 64 + lane;      // always <= q
        float s = -1e9f;
        if (ka >= 0) {
            float acc = 0.f;
#pragma unroll
            for (int j = 0; j < 8; j++) {
                bfrag kv = *(const bfrag*)(&Kg[base + (size_t)ka * NDIM + j * 8]);
#pragma unroll
                for (int e = 0; e < 8; e++)
                    acc += (float)kv[e] * Qrow[wid][j * 8 + e];
            }
            s = acc * 0.125f;
        }
        sc[i] = s;
    }

    float m = -1e9f;
#pragma unroll
    for (int i = 0; i < 8; i++) m = fmaxf(m, sc[i]);
#pragma unroll
    for (int d = 1; d < 64; d <<= 1) m = fmaxf(m, __shfl_xor(m, d, 64));
    float sum = 0.f;
#pragma unroll
    for (int i = 0; i < 8; i++) {
        sc[i] = __expf(sc[i] - m);
        sum += sc[i];
    }
#pragma unroll
    for (int d = 1; d < 64; d <<= 1) sum += __shfl_xor(sum, d, 64);
    const float invs = 1.0f / sum;

#pragma unroll
    for (int i = 0; i < 8; i++)
        Prow[wid][i * 64 + lane] = sc[i] * invs;
    __syncthreads();

    float o = 0.f;
    for (int i = 0; i < 512; i++) {
        int ka = lo + i;
        if (ka >= 0)
            o += Prow[wid][i] * (float)Vg[base + (size_t)ka * NDIM + lane];
    }
    AO[base + (size_t)q * NDIM + lane] = (bf16_t)o;
}

// ---------------------------------------------------------------------------
extern "C" void kernel_launch(void* const* d_in, const int* in_sizes, int n_in,
                              void* d_out, int out_size, void* d_ws, size_t ws_size,
                              hipStream_t stream)
{
    const float* x  = (const float*)d_in[0];
    const float* Wq = (const float*)d_in[1];
    const float* bq = (const float*)d_in[2];
    const float* Wk = (const float*)d_in[3];
    const float* bk = (const float*)d_in[4];
    const float* Wv = (const float*)d_in[5];
    const float* bv = (const float*)d_in[6];
    const float* Wo = (const float*)d_in[7];
    const float* bo = (const float*)d_in[8];
    float* out = (float*)d_out;

    const size_t nElem = (size_t)MROWS * NDIM;         // 8.39M elems
    if (ws_size < 4 * nElem * sizeof(bf16_t)) return;  // need 67 MB scratch

    bf16_t* Qb = (bf16_t*)d_ws;
    bf16_t* Kb = Qb + nElem;
    bf16_t* Vb = Kb + nElem;
    bf16_t* Ab = Vb + nElem;

    dim3 gemmGrid(NDIM / 128, MROWS / 128);   // (8, 64)
    dim3 blk(256);

    gemm_bt<float, bf16_t><<<gemmGrid, blk, 0, stream>>>(x, Wq, bq, Qb, MROWS, NDIM, NDIM);
    gemm_bt<float, bf16_t><<<gemmGrid, blk, 0, stream>>>(x, Wk, bk, Kb, MROWS, NDIM, NDIM);
    gemm_bt<float, bf16_t><<<gemmGrid, blk, 0, stream>>>(x, Wv, bv, Vb, MROWS, NDIM, NDIM);

    dim3 attnGrid(SEQ / 4, NBATCH * NHEAD);   // one wave per query
    attn_naive<<<attnGrid, blk, 0, stream>>>(Qb, Kb, Vb, Ab);

    gemm_bt<bf16_t, float><<<gemmGrid, blk, 0, stream>>>(Ab, Wo, bo, out, MROWS, NDIM, NDIM);
}

// Round 4
// 455.726 us; speedup vs baseline: 5.1196x; 5.1196x over previous
//
#include <hip/hip_runtime.h>
#include <hip/hip_bf16.h>

typedef __bf16 bf16_t;
typedef __attribute__((ext_vector_type(8))) __bf16 bfrag;   // 8 bf16 = 4 VGPRs (MFMA A/B frag)
typedef __attribute__((ext_vector_type(4))) float f32x4;    // MFMA C/D frag

#define SEQ    4096
#define NDIM   1024
#define NHEAD  16
#define HD     64
#define NBATCH 2
#define MROWS  (NBATCH * SEQ)   // 8192

// ---------------------------------------------------------------------------
// GEMM: C[M,N] = A[M,K] @ W[N,K]^T + bias[N]
// A: fp32 or bf16 (templated), W/bias: fp32, C: fp32 or bf16 (templated).
// fp32 operands are cast to bf16 during LDS staging; accumulate fp32 in MFMA.
// 128x128 tile, BK=32, 256 threads = 4 waves (2x2), each wave 64x64 = 4x4 MFMA.
// C/D layout: col = lane&15, row = quad*4 + reg (validated end-to-end R3).
// ---------------------------------------------------------------------------
template <typename AT, typename OT>
__global__ __launch_bounds__(256, 2)
void gemm_bt(const AT* __restrict__ A, const float* __restrict__ W,
             const float* __restrict__ bias, OT* __restrict__ C,
             int M, int N, int K)
{
    __shared__ __align__(16) bf16_t As[128 * 32];
    __shared__ __align__(16) bf16_t Bs[128 * 32];

    const int tid  = threadIdx.x;
    const int lane = tid & 63;
    const int wid  = tid >> 6;
    const int n16  = lane & 15;
    const int quad = lane >> 4;
    const int row0 = blockIdx.y * 128;
    const int col0 = blockIdx.x * 128;
    const int wrow = (wid >> 1) * 64;
    const int wcol = (wid & 1) * 64;

    f32x4 acc[4][4];
#pragma unroll
    for (int i = 0; i < 4; i++)
#pragma unroll
        for (int j = 0; j < 4; j++) acc[i][j] = (f32x4){0.f, 0.f, 0.f, 0.f};

    for (int k0 = 0; k0 < K; k0 += 32) {
        // ---- stage A tile (128 x 32) ----
        if constexpr (sizeof(AT) == 4) {
#pragma unroll
            for (int it = 0; it < 4; it++) {
                int idx = tid + it * 256;        // 0..1023
                int r   = idx >> 3;              // 0..127
                int c   = (idx & 7) * 4;         // 0,4,...,28
                float4 v = *(const float4*)(&A[(size_t)(row0 + r) * K + k0 + c]);
                bf16_t* p = &As[r * 32 + c];
                p[0] = (bf16_t)v.x; p[1] = (bf16_t)v.y;
                p[2] = (bf16_t)v.z; p[3] = (bf16_t)v.w;
            }
        } else {
#pragma unroll
            for (int it = 0; it < 2; it++) {
                int idx = tid + it * 256;        // 0..511
                int r   = idx >> 2;
                int c   = (idx & 3) * 8;
                *(uint4*)(&As[r * 32 + c]) = *(const uint4*)(&A[(size_t)(row0 + r) * K + k0 + c]);
            }
        }
        // ---- stage W tile (128 x 32), always fp32 source ----
#pragma unroll
        for (int it = 0; it < 4; it++) {
            int idx = tid + it * 256;
            int r   = idx >> 3;
            int c   = (idx & 7) * 4;
            float4 v = *(const float4*)(&W[(size_t)(col0 + r) * K + k0 + c]);
            bf16_t* p = &Bs[r * 32 + c];
            p[0] = (bf16_t)v.x; p[1] = (bf16_t)v.y;
            p[2] = (bf16_t)v.z; p[3] = (bf16_t)v.w;
        }
        __syncthreads();

        bfrag af[4], bfg[4];
#pragma unroll
        for (int i = 0; i < 4; i++)
            af[i] = *(const bfrag*)(&As[(wrow + i * 16 + n16) * 32 + quad * 8]);
#pragma unroll
        for (int j = 0; j < 4; j++)
            bfg[j] = *(const bfrag*)(&Bs[(wcol + j * 16 + n16) * 32 + quad * 8]);

#pragma unroll
        for (int i = 0; i < 4; i++)
#pragma unroll
            for (int j = 0; j < 4; j++)
                acc[i][j] = __builtin_amdgcn_mfma_f32_16x16x32_bf16(af[i], bfg[j], acc[i][j], 0, 0, 0);
        __syncthreads();
    }

    // ---- epilogue: add bias (fp32), store ----
#pragma unroll
    for (int i = 0; i < 4; i++) {
#pragma unroll
        for (int j = 0; j < 4; j++) {
#pragma unroll
            for (int r = 0; r < 4; r++) {
                int row = row0 + wrow + i * 16 + quad * 4 + r;
                int col = col0 + wcol + j * 16 + n16;
                float v = acc[i][j][r] + bias[col];
                C[(size_t)row * N + col] = (OT)v;
            }
        }
    }
}

// ---------------------------------------------------------------------------
// MFMA sliding-window attention. One workgroup = (b, h, 64-query tile),
// 4 waves; each wave owns 16 queries. Key window: kw in [0,576),
// kabs = q0-512+kw; query qa attends kabs in [qa-511, qa] ∩ [0,S).
// Phase A: S = Q K^T via MFMA (K B-frags direct from global, L2-resident),
//          mask + softmax in C-layout registers (16-lane shfl groups),
//          normalized P -> LDS bf16 (A-operand row-major).
// Phase B: O = P V via MFMA; V transposed into 32-key LDS chunks.
// ---------------------------------------------------------------------------
__global__ __launch_bounds__(256, 2)
void attn_win(const bf16_t* __restrict__ Q, const bf16_t* __restrict__ Kg,
              const bf16_t* __restrict__ Vg, bf16_t* __restrict__ AO)
{
    __shared__ __align__(16) bf16_t P[64 * 584];   // 74752 B; stride 584 elems (16B-aligned rows)
    __shared__ __align__(16) bf16_t Vt[64 * 40];   // 5120 B; [dim][key] chunk, pad 40

    const int tid  = threadIdx.x;
    const int wid  = tid >> 6;
    const int lane = tid & 63;
    const int n16  = lane & 15;
    const int quad = lane >> 4;

    const int q0 = blockIdx.x * 64;
    const int bh = blockIdx.y;           // b*NHEAD + h
    const int b  = bh >> 4;
    const int h  = bh & 15;
    const size_t base   = (size_t)b * SEQ * NDIM + (size_t)h * HD;  // + s*NDIM + d
    const int    wstart = q0 - 512;

    // ---- Phase A: scores ----
    const int mq = wid * 16 + n16;       // A-frag query (local row m = lane&15)
    bfrag aq0 = *(const bfrag*)(&Q[base + (size_t)(q0 + mq) * NDIM + quad * 8]);
    bfrag aq1 = *(const bfrag*)(&Q[base + (size_t)(q0 + mq) * NDIM + 32 + quad * 8]);

    bfrag bz;
#pragma unroll
    for (int e = 0; e < 8; e++) bz[e] = (__bf16)0.f;

    float sc[36][4];
#pragma unroll
    for (int nt = 0; nt < 36; nt++) {
        int kw   = nt * 16 + n16;        // this lane's key (B-frag n / C col)
        int kabs = wstart + kw;
        bfrag b0 = bz, b1 = bz;
        if (kabs >= 0) {
            b0 = *(const bfrag*)(&Kg[base + (size_t)kabs * NDIM + quad * 8]);
            b1 = *(const bfrag*)(&Kg[base + (size_t)kabs * NDIM + 32 + quad * 8]);
        }
        f32x4 a = (f32x4){0.f, 0.f, 0.f, 0.f};
        a = __builtin_amdgcn_mfma_f32_16x16x32_bf16(aq0, b0, a, 0, 0, 0);
        a = __builtin_amdgcn_mfma_f32_16x16x32_bf16(aq1, b1, a, 0, 0, 0);
#pragma unroll
        for (int r = 0; r < 4; r++) {
            int qa = q0 + wid * 16 + quad * 4 + r;   // C row = query
            int ka = wstart + nt * 16 + n16;         // C col = key
            bool valid = (ka >= 0) & (ka >= qa - 511) & (ka <= qa);
            sc[nt][r] = valid ? a[r] * 0.125f : -1e30f;
        }
    }

    // ---- softmax per query row (row lives on a 16-lane group) ----
    float inv[4];
#pragma unroll
    for (int r = 0; r < 4; r++) {
        float m = -1e30f;
#pragma unroll
        for (int nt = 0; nt < 36; nt++) m = fmaxf(m, sc[nt][r]);
#pragma unroll
        for (int d = 1; d < 16; d <<= 1) m = fmaxf(m, __shfl_xor(m, d, 64));
        float s = 0.f;
#pragma unroll
        for (int nt = 0; nt < 36; nt++) {
            float p = __expf(sc[nt][r] - m);
            sc[nt][r] = p;
            s += p;
        }
#pragma unroll
        for (int d = 1; d < 16; d <<= 1) s += __shfl_xor(s, d, 64);
        inv[r] = 1.0f / s;
    }

    // ---- write normalized P (bf16) to LDS, A-operand row-major ----
#pragma unroll
    for (int nt = 0; nt < 36; nt++) {
#pragma unroll
        for (int r = 0; r < 4; r++) {
            int lrow = wid * 16 + quad * 4 + r;
            P[lrow * 584 + nt * 16 + n16] = (bf16_t)(sc[nt][r] * inv[r]);
        }
    }

    // ---- Phase B: O = P @ V, 18 k-steps of 32 keys ----
    f32x4 ao[4];
#pragma unroll
    for (int j = 0; j < 4; j++) ao[j] = (f32x4){0.f, 0.f, 0.f, 0.f};

    for (int ks = 0; ks < 18; ks++) {
        __syncthreads();                 // Vt reuse fence (P rows are wave-private)
        {   // stage Vt[dim][key]: 32 keys x 64 dims, transposed
            int kk = tid >> 3;           // key within chunk
            int dh = tid & 7;            // dim group: dims dh*8..dh*8+7
            int ka = wstart + ks * 32 + kk;
            bfrag v = bz;
            if (ka >= 0)
                v = *(const bfrag*)(&Vg[base + (size_t)ka * NDIM + dh * 8]);
#pragma unroll
            for (int e = 0; e < 8; e++) Vt[(dh * 8 + e) * 40 + kk] = v[e];
        }
        __syncthreads();

        bfrag ap = *(const bfrag*)(&P[(wid * 16 + n16) * 584 + ks * 32 + quad * 8]);
#pragma unroll
        for (int j = 0; j < 4; j++) {
            bfrag bv = *(const bfrag*)(&Vt[(j * 16 + n16) * 40 + quad * 8]);
            ao[j] = __builtin_amdgcn_mfma_f32_16x16x32_bf16(ap, bv, ao[j], 0, 0, 0);
        }
    }

    // ---- epilogue: AO[b*S+qa][h*64+d] ----
#pragma unroll
    for (int j = 0; j < 4; j++) {
#pragma unroll
        for (int r = 0; r < 4; r++) {
            int qa = q0 + wid * 16 + quad * 4 + r;
            AO[base + (size_t)qa * NDIM + j * 16 + n16] = (bf16_t)ao[j][r];
        }
    }
}

// ---------------------------------------------------------------------------
extern "C" void kernel_launch(void* const* d_in, const int* in_sizes, int n_in,
                              void* d_out, int out_size, void* d_ws, size_t ws_size,
                              hipStream_t stream)
{
    const float* x  = (const float*)d_in[0];
    const float* Wq = (const float*)d_in[1];
    const float* bq = (const float*)d_in[2];
    const float* Wk = (const float*)d_in[3];
    const float* bk = (const float*)d_in[4];
    const float* Wv = (const float*)d_in[5];
    const float* bv = (const float*)d_in[6];
    const float* Wo = (const float*)d_in[7];
    const float* bo = (const float*)d_in[8];
    float* out = (float*)d_out;

    const size_t nElem = (size_t)MROWS * NDIM;         // 8.39M elems
    if (ws_size < 4 * nElem * sizeof(bf16_t)) return;  // need 67 MB scratch

    bf16_t* Qb = (bf16_t*)d_ws;
    bf16_t* Kb = Qb + nElem;
    bf16_t* Vb = Kb + nElem;
    bf16_t* Ab = Vb + nElem;

    dim3 gemmGrid(NDIM / 128, MROWS / 128);   // (8, 64)
    dim3 blk(256);

    gemm_bt<float, bf16_t><<<gemmGrid, blk, 0, stream>>>(x, Wq, bq, Qb, MROWS, NDIM, NDIM);
    gemm_bt<float, bf16_t><<<gemmGrid, blk, 0, stream>>>(x, Wk, bk, Kb, MROWS, NDIM, NDIM);
    gemm_bt<float, bf16_t><<<gemmGrid, blk, 0, stream>>>(x, Wv, bv, Vb, MROWS, NDIM, NDIM);

    dim3 attnGrid(SEQ / 64, NBATCH * NHEAD);  // (64, 32)
    attn_win<<<attnGrid, blk, 0, stream>>>(Qb, Kb, Vb, Ab);

    gemm_bt<bf16_t, float><<<gemmGrid, blk, 0, stream>>>(Ab, Wo, bo, out, MROWS, NDIM, NDIM);
}

// Round 5
// 299.669 us; speedup vs baseline: 7.7857x; 1.5208x over previous
//
#include <hip/hip_runtime.h>
#include <hip/hip_bf16.h>

typedef __bf16 bf16_t;
typedef __attribute__((ext_vector_type(8))) __bf16 bfrag;   // 8 bf16 = 4 VGPRs (MFMA A/B frag)
typedef __attribute__((ext_vector_type(4))) float f32x4;    // MFMA C/D frag

#define SEQ    4096
#define NDIM   1024
#define NHEAD  16
#define HD     64
#define NBATCH 2
#define MROWS  (NBATCH * SEQ)   // 8192
#define LQKV   3072             // fused QKV row stride

// async 16B global -> LDS (m97 pattern). l must be wave-uniform; lane i lands at l + i*16.
__device__ __forceinline__ void gload_lds16(const bf16_t* g, bf16_t* l) {
    __builtin_amdgcn_global_load_lds(
        (const __attribute__((address_space(1))) unsigned int*)g,
        (__attribute__((address_space(3))) unsigned int*)l,
        16, 0, 0);
}

// ---------------------------------------------------------------------------
// GEMM: C[M,N] = A[M,K] @ W[N,K]^T + bias   (bf16 in, f32 acc, OT out)
// m97 structure: 128x128 tile, BK=32, global_load_lds width-16 staging.
// bias selected per 128-col block: cols [0,1024) -> b0, [1024,2048) -> b1, else b2.
// ---------------------------------------------------------------------------
template <typename OT>
__global__ __launch_bounds__(256, 2)
void gemm_bt(const bf16_t* __restrict__ A, int lda,
             const bf16_t* __restrict__ W,
             const float* __restrict__ b0p, const float* __restrict__ b1p,
             const float* __restrict__ b2p,
             OT* __restrict__ C, int ldc, int K)
{
    __shared__ __align__(16) bf16_t As[128 * 32];
    __shared__ __align__(16) bf16_t Bs[128 * 32];

    const int tid  = threadIdx.x;
    const int lane = tid & 63;
    const int wid  = tid >> 6;
    const int n16  = lane & 15;
    const int quad = lane >> 4;
    const int row0 = blockIdx.y * 128;
    const int col0 = blockIdx.x * 128;
    const int wrow = (wid >> 1) * 64;
    const int wcol = (wid & 1) * 64;
    const float* bias = (col0 < 1024) ? b0p : (col0 < 2048 ? b1p : b2p);
    const int bcol0 = col0 & 1023;

    f32x4 acc[4][4];
#pragma unroll
    for (int i = 0; i < 4; i++)
#pragma unroll
        for (int j = 0; j < 4; j++) acc[i][j] = (f32x4){0.f, 0.f, 0.f, 0.f};

    for (int k0 = 0; k0 < K; k0 += 32) {
        // ---- async stage A/W tiles (128x32 bf16 each) ----
#pragma unroll
        for (int it = 0; it < 2; it++) {
            int idx = tid + it * 256;          // 16B-chunk index 0..511
            int r   = idx >> 2;
            int c   = (idx & 3) * 8;
            gload_lds16(A + (size_t)(row0 + r) * lda + k0 + c, &As[(it * 256 + wid * 64) * 8]);
            gload_lds16(W + (size_t)(col0 + r) * K   + k0 + c, &Bs[(it * 256 + wid * 64) * 8]);
        }
        __syncthreads();

        bfrag af[4], bfg[4];
#pragma unroll
        for (int i = 0; i < 4; i++)
            af[i] = *(const bfrag*)(&As[(wrow + i * 16 + n16) * 32 + quad * 8]);
#pragma unroll
        for (int j = 0; j < 4; j++)
            bfg[j] = *(const bfrag*)(&Bs[(wcol + j * 16 + n16) * 32 + quad * 8]);

#pragma unroll
        for (int i = 0; i < 4; i++)
#pragma unroll
            for (int j = 0; j < 4; j++)
                acc[i][j] = __builtin_amdgcn_mfma_f32_16x16x32_bf16(af[i], bfg[j], acc[i][j], 0, 0, 0);
        __syncthreads();
    }

#pragma unroll
    for (int i = 0; i < 4; i++) {
#pragma unroll
        for (int j = 0; j < 4; j++) {
#pragma unroll
            for (int r = 0; r < 4; r++) {
                int row = row0 + wrow + i * 16 + quad * 4 + r;
                int col = wcol + j * 16 + n16;
                float v = acc[i][j][r] + bias[bcol0 + col];
                C[(size_t)row * ldc + col0 + col] = (OT)v;
            }
        }
    }
}

// ---------------------------------------------------------------------------
// fp32 -> bf16 casts
// ---------------------------------------------------------------------------
__global__ __launch_bounds__(256)
void cast_x(const float* __restrict__ s, bf16_t* __restrict__ d)
{
    size_t i = ((size_t)blockIdx.x * 256 + threadIdx.x) * 8;
    float4 a = *(const float4*)(s + i);
    float4 b = *(const float4*)(s + i + 4);
    bfrag o;
    o[0] = (__bf16)a.x; o[1] = (__bf16)a.y; o[2] = (__bf16)a.z; o[3] = (__bf16)a.w;
    o[4] = (__bf16)b.x; o[5] = (__bf16)b.y; o[6] = (__bf16)b.z; o[7] = (__bf16)b.w;
    *(bfrag*)(d + i) = o;
}

__global__ __launch_bounds__(256)
void cast_w(const float* __restrict__ wq, const float* __restrict__ wk,
            const float* __restrict__ wv, const float* __restrict__ wo,
            bf16_t* __restrict__ d)   // d = [Wq|Wk|Wv|Wo] bf16, 4x 1M elems
{
    size_t t   = (size_t)blockIdx.x * 256 + threadIdx.x;   // 0..524287
    int    sel = (int)(t >> 17);                           // 131072 chunks per W
    const float* s = sel == 0 ? wq : (sel == 1 ? wk : (sel == 2 ? wv : wo));
    size_t off = (t & 131071) * 8;
    float4 a = *(const float4*)(s + off);
    float4 b = *(const float4*)(s + off + 4);
    bfrag o;
    o[0] = (__bf16)a.x; o[1] = (__bf16)a.y; o[2] = (__bf16)a.z; o[3] = (__bf16)a.w;
    o[4] = (__bf16)b.x; o[5] = (__bf16)b.y; o[6] = (__bf16)b.z; o[7] = (__bf16)b.w;
    *(bfrag*)(d + (size_t)sel * 1048576 + off) = o;
}

// ---------------------------------------------------------------------------
// MFMA sliding-window attention. One workgroup = (b, h, 64-query tile), 4 waves.
// QKV fused input: row stride 3072, Q at +0, K at +1024, V at +2048.
// Phase A: K staged in 32-key LDS chunks (coalesced, reg-prefetched); S = QK^T
//          via MFMA, mask+softmax in C-layout regs, normalized P -> LDS bf16.
// Phase B: V transposed into LDS (stride 34: conflict-free), O = PV via MFMA.
// ---------------------------------------------------------------------------
__global__ __launch_bounds__(256, 2)
void attn_win(const bf16_t* __restrict__ QKV, bf16_t* __restrict__ AO)
{
    __shared__ __align__(16) bf16_t P[64 * 584];   // 74752 B
    __shared__ __align__(16) bf16_t KV[2304];      // 4608 B: Ks[32][72] / Vt[64][34] union

    const int tid  = threadIdx.x;
    const int wid  = tid >> 6;
    const int lane = tid & 63;
    const int n16  = lane & 15;
    const int quad = lane >> 4;
    const int r32  = tid >> 3;          // staging: key-in-chunk 0..31
    const int cg   = (tid & 7) * 8;     // staging: dim group

    const int q0 = blockIdx.x * 64;
    const int bh = blockIdx.y;
    const int b  = bh >> 4;
    const int h  = bh & 15;
    const size_t bS   = (size_t)b * SEQ;
    const size_t hoff = (size_t)h * HD;
    const int wstart  = q0 - 512;

    // ---- Q A-frags (once) ----
    const int mq = wid * 16 + n16;
    bfrag aq0 = *(const bfrag*)(&QKV[(bS + q0 + mq) * LQKV + hoff + quad * 8]);
    bfrag aq1 = *(const bfrag*)(&QKV[(bS + q0 + mq) * LQKV + hoff + 32 + quad * 8]);

    const uint4 z4 = (uint4){0u, 0u, 0u, 0u};

    // ---- Phase A: 18 chunks of 32 keys, reg-prefetched K staging ----
    uint4 kpre;
    {
        int ka = wstart + r32;
        kpre = (ka >= 0) ? *(const uint4*)(&QKV[(bS + ka) * LQKV + 1024 + hoff + cg]) : z4;
    }

    float sc[36][4];
    for (int ck = 0; ck < 18; ck++) {
        __syncthreads();
        *(uint4*)(&KV[r32 * 72 + cg]) = kpre;
        __syncthreads();
        if (ck < 17) {
            int ka = wstart + (ck + 1) * 32 + r32;
            kpre = (ka >= 0) ? *(const uint4*)(&QKV[(bS + ka) * LQKV + 1024 + hoff + cg]) : z4;
        }
#pragma unroll
        for (int t = 0; t < 2; t++) {
            int nt = ck * 2 + t;
            bfrag b0 = *(const bfrag*)(&KV[(t * 16 + n16) * 72 + quad * 8]);
            bfrag b1 = *(const bfrag*)(&KV[(t * 16 + n16) * 72 + 32 + quad * 8]);
            f32x4 a = (f32x4){0.f, 0.f, 0.f, 0.f};
            a = __builtin_amdgcn_mfma_f32_16x16x32_bf16(aq0, b0, a, 0, 0, 0);
            a = __builtin_amdgcn_mfma_f32_16x16x32_bf16(aq1, b1, a, 0, 0, 0);
#pragma unroll
            for (int r = 0; r < 4; r++) {
                int qa = q0 + wid * 16 + quad * 4 + r;
                int ka = wstart + nt * 16 + n16;
                bool valid = (ka >= 0) & (ka >= qa - 511) & (ka <= qa);
                sc[nt][r] = valid ? a[r] * 0.125f : -1e30f;
            }
        }
    }

    // ---- softmax per query row (16-lane groups) ----
    float inv[4];
#pragma unroll
    for (int r = 0; r < 4; r++) {
        float m = -1e30f;
#pragma unroll
        for (int nt = 0; nt < 36; nt++) m = fmaxf(m, sc[nt][r]);
#pragma unroll
        for (int d = 1; d < 16; d <<= 1) m = fmaxf(m, __shfl_xor(m, d, 64));
        float s = 0.f;
#pragma unroll
        for (int nt = 0; nt < 36; nt++) {
            float p = __expf(sc[nt][r] - m);
            sc[nt][r] = p;
            s += p;
        }
#pragma unroll
        for (int d = 1; d < 16; d <<= 1) s += __shfl_xor(s, d, 64);
        inv[r] = 1.0f / s;
    }

#pragma unroll
    for (int nt = 0; nt < 36; nt++) {
#pragma unroll
        for (int r = 0; r < 4; r++) {
            int lrow = wid * 16 + quad * 4 + r;
            P[lrow * 584 + nt * 16 + n16] = (bf16_t)(sc[nt][r] * inv[r]);
        }
    }

    // ---- Phase B: O = P @ V, 18 chunks of 32 keys, reg-prefetched V staging ----
    f32x4 ao[4];
#pragma unroll
    for (int j = 0; j < 4; j++) ao[j] = (f32x4){0.f, 0.f, 0.f, 0.f};

    uint4 vpre;
    {
        int ka = wstart + r32;
        vpre = (ka >= 0) ? *(const uint4*)(&QKV[(bS + ka) * LQKV + 2048 + hoff + cg]) : z4;
    }

    for (int ks = 0; ks < 18; ks++) {
        __syncthreads();                 // protects KV reuse (Ks of last A-chunk / prev Vt)
        {   // transpose 16B of key r32 (dims cg..cg+7) into Vt[dim][key], stride 34
            bfrag vv = *(bfrag*)&vpre;
#pragma unroll
            for (int e = 0; e < 8; e++) KV[(cg + e) * 34 + r32] = vv[e];
        }
        __syncthreads();
        if (ks < 17) {
            int ka = wstart + (ks + 1) * 32 + r32;
            vpre = (ka >= 0) ? *(const uint4*)(&QKV[(bS + ka) * LQKV + 2048 + hoff + cg]) : z4;
        }

        bfrag ap = *(const bfrag*)(&P[(wid * 16 + n16) * 584 + ks * 32 + quad * 8]);
#pragma unroll
        for (int j = 0; j < 4; j++) {
            bfrag bv = *(const bfrag*)(&KV[(j * 16 + n16) * 34 + quad * 8]);
            ao[j] = __builtin_amdgcn_mfma_f32_16x16x32_bf16(ap, bv, ao[j], 0, 0, 0);
        }
    }

    // ---- epilogue: AO[bS+qa][h*64+d], row stride 1024 ----
#pragma unroll
    for (int j = 0; j < 4; j++) {
#pragma unroll
        for (int r = 0; r < 4; r++) {
            int qa = q0 + wid * 16 + quad * 4 + r;
            AO[(bS + qa) * NDIM + hoff + j * 16 + n16] = (bf16_t)ao[j][r];
        }
    }
}

// ---------------------------------------------------------------------------
extern "C" void kernel_launch(void* const* d_in, const int* in_sizes, int n_in,
                              void* d_out, int out_size, void* d_ws, size_t ws_size,
                              hipStream_t stream)
{
    const float* x  = (const float*)d_in[0];
    const float* Wq = (const float*)d_in[1];
    const float* bq = (const float*)d_in[2];
    const float* Wk = (const float*)d_in[3];
    const float* bk = (const float*)d_in[4];
    const float* Wv = (const float*)d_in[5];
    const float* bv = (const float*)d_in[6];
    const float* Wo = (const float*)d_in[7];
    const float* bo = (const float*)d_in[8];
    float* out = (float*)d_out;

    // ws layout (72 MiB):
    //   QKVb [8192][3072] bf16 : 48 MiB
    //   AbX  [8192][1024] bf16 : 16 MiB  (x_bf16 during QKV GEMM, then attention out)
    //   Wc   [Wq|Wk|Wv|Wo] bf16:  8 MiB
    const size_t QKV_E = (size_t)MROWS * LQKV;     // 25165824
    const size_t X_E   = (size_t)MROWS * NDIM;     // 8388608
    if (ws_size < (QKV_E + X_E + 4u * 1048576u) * sizeof(bf16_t)) return;

    bf16_t* QKVb = (bf16_t*)d_ws;
    bf16_t* AbX  = QKVb + QKV_E;
    bf16_t* Wc   = AbX + X_E;
    bf16_t* Wob  = Wc + 3u * 1048576u;

    dim3 blk(256);

    cast_x<<<dim3(4096), blk, 0, stream>>>(x, AbX);
    cast_w<<<dim3(2048), blk, 0, stream>>>(Wq, Wk, Wv, Wo, Wc);

    // fused QKV projection: [8192,1024] x [3072,1024]^T -> [8192,3072]
    gemm_bt<bf16_t><<<dim3(LQKV / 128, MROWS / 128), blk, 0, stream>>>(
        AbX, NDIM, Wc, bq, bk, bv, QKVb, LQKV, NDIM);

    attn_win<<<dim3(SEQ / 64, NBATCH * NHEAD), blk, 0, stream>>>(QKVb, AbX);

    // output projection: [8192,1024] x [1024,1024]^T -> fp32 out
    gemm_bt<float><<<dim3(NDIM / 128, MROWS / 128), blk, 0, stream>>>(
        AbX, NDIM, Wob, bo, bo, bo, out, NDIM, NDIM);
}

// Round 6
// 291.836 us; speedup vs baseline: 7.9947x; 1.0268x over previous
//
#include <hip/hip_runtime.h>
#include <hip/hip_bf16.h>

typedef __bf16 bf16_t;
typedef __attribute__((ext_vector_type(8))) __bf16 bfrag;   // 8 bf16 = 4 VGPRs (MFMA A/B frag)
typedef __attribute__((ext_vector_type(4))) float f32x4;    // MFMA C/D frag

#define SEQ    4096
#define NDIM   1024
#define NHEAD  16
#define HD     64
#define NBATCH 2
#define MROWS  (NBATCH * SEQ)   // 8192
#define LQKV   3072             // fused QKV row stride

// async 16B global -> LDS (m97 pattern). l must be wave-uniform; lane i lands at l + i*16.
__device__ __forceinline__ void gload_lds16(const bf16_t* g, bf16_t* l) {
    __builtin_amdgcn_global_load_lds(
        (const __attribute__((address_space(1))) unsigned int*)g,
        (__attribute__((address_space(3))) unsigned int*)l,
        16, 0, 0);
}

// DPP cross-lane reduce over each contiguous 16-lane group (VALU pipe, no LDS).
#define DPPF(v, ctrl) __builtin_bit_cast(float, \
    __builtin_amdgcn_update_dpp(0, __builtin_bit_cast(int, (v)), (ctrl), 0xF, 0xF, true))

__device__ __forceinline__ float rowmax16(float v) {
    v = fmaxf(v, DPPF(v, 0xB1));    // quad_perm (1,0,3,2)  = xor 1
    v = fmaxf(v, DPPF(v, 0x4E));    // quad_perm (2,3,0,1)  = xor 2
    v = fmaxf(v, DPPF(v, 0x141));   // row_half_mirror      = xor 7
    v = fmaxf(v, DPPF(v, 0x140));   // row_mirror           = xor 15
    return v;
}
__device__ __forceinline__ float rowsum16(float v) {
    v += DPPF(v, 0xB1);
    v += DPPF(v, 0x4E);
    v += DPPF(v, 0x141);
    v += DPPF(v, 0x140);
    return v;
}

// ---------------------------------------------------------------------------
// GEMM: C[M,N] = A[M,K] @ W[N,K]^T + bias   (bf16 in, f32 acc, OT out)
// m97 structure: 128x128 tile, BK=32, global_load_lds width-16 staging.
// ---------------------------------------------------------------------------
template <typename OT>
__global__ __launch_bounds__(256, 2)
void gemm_bt(const bf16_t* __restrict__ A, int lda,
             const bf16_t* __restrict__ W,
             const float* __restrict__ b0p, const float* __restrict__ b1p,
             const float* __restrict__ b2p,
             OT* __restrict__ C, int ldc, int K)
{
    __shared__ __align__(16) bf16_t As[128 * 32];
    __shared__ __align__(16) bf16_t Bs[128 * 32];

    const int tid  = threadIdx.x;
    const int lane = tid & 63;
    const int wid  = tid >> 6;
    const int n16  = lane & 15;
    const int quad = lane >> 4;
    const int row0 = blockIdx.y * 128;
    const int col0 = blockIdx.x * 128;
    const int wrow = (wid >> 1) * 64;
    const int wcol = (wid & 1) * 64;
    const float* bias = (col0 < 1024) ? b0p : (col0 < 2048 ? b1p : b2p);
    const int bcol0 = col0 & 1023;

    f32x4 acc[4][4];
#pragma unroll
    for (int i = 0; i < 4; i++)
#pragma unroll
        for (int j = 0; j < 4; j++) acc[i][j] = (f32x4){0.f, 0.f, 0.f, 0.f};

    for (int k0 = 0; k0 < K; k0 += 32) {
#pragma unroll
        for (int it = 0; it < 2; it++) {
            int idx = tid + it * 256;          // 16B-chunk index 0..511
            int r   = idx >> 2;
            int c   = (idx & 3) * 8;
            gload_lds16(A + (size_t)(row0 + r) * lda + k0 + c, &As[(it * 256 + wid * 64) * 8]);
            gload_lds16(W + (size_t)(col0 + r) * K   + k0 + c, &Bs[(it * 256 + wid * 64) * 8]);
        }
        __syncthreads();

        bfrag af[4], bfg[4];
#pragma unroll
        for (int i = 0; i < 4; i++)
            af[i] = *(const bfrag*)(&As[(wrow + i * 16 + n16) * 32 + quad * 8]);
#pragma unroll
        for (int j = 0; j < 4; j++)
            bfg[j] = *(const bfrag*)(&Bs[(wcol + j * 16 + n16) * 32 + quad * 8]);

#pragma unroll
        for (int i = 0; i < 4; i++)
#pragma unroll
            for (int j = 0; j < 4; j++)
                acc[i][j] = __builtin_amdgcn_mfma_f32_16x16x32_bf16(af[i], bfg[j], acc[i][j], 0, 0, 0);
        __syncthreads();
    }

#pragma unroll
    for (int i = 0; i < 4; i++) {
#pragma unroll
        for (int j = 0; j < 4; j++) {
#pragma unroll
            for (int r = 0; r < 4; r++) {
                int row = row0 + wrow + i * 16 + quad * 4 + r;
                int col = wcol + j * 16 + n16;
                float v = acc[i][j][r] + bias[bcol0 + col];
                C[(size_t)row * ldc + col0 + col] = (OT)v;
            }
        }
    }
}

// ---------------------------------------------------------------------------
// fp32 -> bf16 casts
// ---------------------------------------------------------------------------
__global__ __launch_bounds__(256)
void cast_x(const float* __restrict__ s, bf16_t* __restrict__ d)
{
    size_t i = ((size_t)blockIdx.x * 256 + threadIdx.x) * 8;
    float4 a = *(const float4*)(s + i);
    float4 b = *(const float4*)(s + i + 4);
    bfrag o;
    o[0] = (__bf16)a.x; o[1] = (__bf16)a.y; o[2] = (__bf16)a.z; o[3] = (__bf16)a.w;
    o[4] = (__bf16)b.x; o[5] = (__bf16)b.y; o[6] = (__bf16)b.z; o[7] = (__bf16)b.w;
    *(bfrag*)(d + i) = o;
}

__global__ __launch_bounds__(256)
void cast_w(const float* __restrict__ wq, const float* __restrict__ wk,
            const float* __restrict__ wv, const float* __restrict__ wo,
            bf16_t* __restrict__ d)   // d = [Wq|Wk|Wv|Wo] bf16
{
    size_t t   = (size_t)blockIdx.x * 256 + threadIdx.x;   // 0..524287
    int    sel = (int)(t >> 17);
    const float* s = sel == 0 ? wq : (sel == 1 ? wk : (sel == 2 ? wv : wo));
    size_t off = (t & 131071) * 8;
    float4 a = *(const float4*)(s + off);
    float4 b = *(const float4*)(s + off + 4);
    bfrag o;
    o[0] = (__bf16)a.x; o[1] = (__bf16)a.y; o[2] = (__bf16)a.z; o[3] = (__bf16)a.w;
    o[4] = (__bf16)b.x; o[5] = (__bf16)b.y; o[6] = (__bf16)b.z; o[7] = (__bf16)b.w;
    *(bfrag*)(d + (size_t)sel * 1048576 + off) = o;
}

// ---------------------------------------------------------------------------
// V transpose: QKV V-section [token][2048+h*64+d] -> Vt[b][h][d][s]
// One block per (64-token tile, bh). LDS 64x72 tile.
// ---------------------------------------------------------------------------
__global__ __launch_bounds__(256, 2)
void vtrans(const bf16_t* __restrict__ QKV, bf16_t* __restrict__ Vt)
{
    __shared__ __align__(16) bf16_t T[64 * 72];
    const int tid = threadIdx.x;
    const int s0  = blockIdx.x * 64;
    const int bh  = blockIdx.y;
    const int b   = bh >> 4, h = bh & 15;
    const size_t bS   = (size_t)b * SEQ;
    const size_t hoff = (size_t)h * HD;

#pragma unroll
    for (int u = 0; u < 2; u++) {
        int idx = tid + u * 256;           // 0..511
        int t = idx >> 3, c = (idx & 7) * 8;
        *(uint4*)&T[t * 72 + c] =
            *(const uint4*)&QKV[(bS + s0 + t) * LQKV + 2048 + hoff + c];
    }
    __syncthreads();
#pragma unroll
    for (int u = 0; u < 2; u++) {
        int idx = tid + u * 256;
        int d = idx >> 3, t8 = (idx & 7) * 8;
        bfrag v;
#pragma unroll
        for (int e = 0; e < 8; e++) v[e] = T[(t8 + e) * 72 + d];
        *(bfrag*)&Vt[((size_t)bh * HD + d) * SEQ + s0 + t8] = v;
    }
}

// ---------------------------------------------------------------------------
// Flash sliding-window attention. Block = (b,h, 64-query tile), 4 waves x 16q.
// 9 iterations of 64 keys; K staged in LDS (dbuf, 1 barrier/iter); V read
// direct from Vt[b][h][d][s] global in B-frag layout; online softmax with
// DPP 16-lane reductions; P chunk through wave-private LDS (no barrier).
// ---------------------------------------------------------------------------
__global__ __launch_bounds__(256, 4)
void attn_win(const bf16_t* __restrict__ QKV, const bf16_t* __restrict__ Vt,
              bf16_t* __restrict__ AO)
{
    __shared__ __align__(16) bf16_t Ks[2][64 * 72];   // 18432 B
    __shared__ __align__(16) bf16_t Pw[4][16 * 72];   //  9216 B, wave-private

    const int tid  = threadIdx.x;
    const int wid  = tid >> 6;
    const int lane = tid & 63;
    const int n16  = lane & 15;
    const int quad = lane >> 4;

    const int q0 = blockIdx.x * 64;
    const int bh = blockIdx.y;
    const int b  = bh >> 4, h = bh & 15;
    const size_t bS   = (size_t)b * SEQ;
    const size_t hoff = (size_t)h * HD;
    const bf16_t* Vb  = Vt + (size_t)bh * HD * SEQ;   // [d][s]
    const int wstart  = q0 - 512;
    const int it0     = (q0 < 512) ? ((512 - q0) >> 6) : 0;

    // staging map: row = tid>>2 (0..63), two 16B chunks per thread
    const int srow  = tid >> 2;
    const int scol0 = (tid & 3) * 16;

    // ---- Q A-frags (scaled scores applied later) ----
    const int mq = wid * 16 + n16;
    bfrag aq0 = *(const bfrag*)(&QKV[(bS + q0 + mq) * LQKV + hoff + quad * 8]);
    bfrag aq1 = *(const bfrag*)(&QKV[(bS + q0 + mq) * LQKV + hoff + 32 + quad * 8]);

    f32x4 ao[4];
#pragma unroll
    for (int j = 0; j < 4; j++) ao[j] = (f32x4){0.f, 0.f, 0.f, 0.f};
    float m[4] = {-1e30f, -1e30f, -1e30f, -1e30f};
    float l[4] = {0.f, 0.f, 0.f, 0.f};

    // prefetch K for first iteration
    uint4 kp0, kp1;
    {
        const bf16_t* src = &QKV[(bS + wstart + it0 * 64 + srow) * LQKV + 1024 + hoff + scol0];
        kp0 = *(const uint4*)(src);
        kp1 = *(const uint4*)(src + 8);
    }

    for (int it = it0; it < 9; ++it) {
        const int pb = it & 1;
        *(uint4*)(&Ks[pb][srow * 72 + scol0])     = kp0;
        *(uint4*)(&Ks[pb][srow * 72 + scol0 + 8]) = kp1;
        __syncthreads();
        if (it < 8) {
            const bf16_t* src = &QKV[(bS + wstart + (it + 1) * 64 + srow) * LQKV + 1024 + hoff + scol0];
            kp0 = *(const uint4*)(src);
            kp1 = *(const uint4*)(src + 8);
        }

        // ---- QK^T: 4 key-tiles x K=64 ----
        f32x4 a[4];
#pragma unroll
        for (int nt = 0; nt < 4; nt++) {
            bfrag b0 = *(const bfrag*)(&Ks[pb][(nt * 16 + n16) * 72 + quad * 8]);
            bfrag b1 = *(const bfrag*)(&Ks[pb][(nt * 16 + n16) * 72 + 32 + quad * 8]);
            f32x4 s4 = (f32x4){0.f, 0.f, 0.f, 0.f};
            s4 = __builtin_amdgcn_mfma_f32_16x16x32_bf16(aq0, b0, s4, 0, 0, 0);
            s4 = __builtin_amdgcn_mfma_f32_16x16x32_bf16(aq1, b1, s4, 0, 0, 0);
            a[nt] = s4;
        }

        const bool msk = (it == 0) || (it == 8);
        if (msk) {
#pragma unroll
            for (int nt = 0; nt < 4; nt++)
#pragma unroll
                for (int r = 0; r < 4; r++) {
                    int ka = wstart + it * 64 + nt * 16 + n16;
                    int qa = q0 + wid * 16 + quad * 4 + r;
                    bool valid = (ka >= qa - 511) & (ka <= qa);
                    a[nt][r] = valid ? a[nt][r] * 0.125f : -1e30f;
                }
        } else {
#pragma unroll
            for (int nt = 0; nt < 4; nt++)
#pragma unroll
                for (int r = 0; r < 4; r++) a[nt][r] *= 0.125f;
        }

        // ---- online softmax state update (DPP reductions) ----
        float alpha[4];
#pragma unroll
        for (int r = 0; r < 4; r++) {
            float cm = fmaxf(fmaxf(a[0][r], a[1][r]), fmaxf(a[2][r], a[3][r]));
            cm = rowmax16(cm);
            float mn = fmaxf(m[r], cm);
            alpha[r] = __expf(m[r] - mn);
            m[r] = mn;
        }
#pragma unroll
        for (int j = 0; j < 4; j++)
#pragma unroll
            for (int r = 0; r < 4; r++) ao[j][r] *= alpha[r];

        // ---- p = exp(s - m), lane-partial l, P chunk -> wave-private LDS ----
        float lacc[4] = {0.f, 0.f, 0.f, 0.f};
#pragma unroll
        for (int nt = 0; nt < 4; nt++) {
#pragma unroll
            for (int r = 0; r < 4; r++) {
                float p;
                if (msk) p = (a[nt][r] > -1e29f) ? __expf(a[nt][r] - m[r]) : 0.f;
                else     p = __expf(a[nt][r] - m[r]);
                lacc[r] += p;
                Pw[wid][(quad * 4 + r) * 72 + nt * 16 + n16] = (bf16_t)p;
            }
        }
#pragma unroll
        for (int r = 0; r < 4; r++) l[r] = l[r] * alpha[r] + lacc[r];

        // ---- PV: P A-frags from Pw (same wave), V B-frags direct from global ----
#pragma unroll
        for (int ks = 0; ks < 2; ks++) {
            bfrag ap = *(const bfrag*)(&Pw[wid][n16 * 72 + ks * 32 + quad * 8]);
#pragma unroll
            for (int j = 0; j < 4; j++) {
                bfrag bv = *(const bfrag*)(&Vb[(size_t)(j * 16 + n16) * SEQ
                                               + wstart + it * 64 + ks * 32 + quad * 8]);
                ao[j] = __builtin_amdgcn_mfma_f32_16x16x32_bf16(ap, bv, ao[j], 0, 0, 0);
            }
        }
    }

    // ---- epilogue ----
    float inv[4];
#pragma unroll
    for (int r = 0; r < 4; r++) inv[r] = 1.0f / rowsum16(l[r]);
#pragma unroll
    for (int j = 0; j < 4; j++)
#pragma unroll
        for (int r = 0; r < 4; r++) {
            int qa = q0 + wid * 16 + quad * 4 + r;
            AO[(bS + qa) * NDIM + hoff + j * 16 + n16] = (bf16_t)(ao[j][r] * inv[r]);
        }
}

// ---------------------------------------------------------------------------
extern "C" void kernel_launch(void* const* d_in, const int* in_sizes, int n_in,
                              void* d_out, int out_size, void* d_ws, size_t ws_size,
                              hipStream_t stream)
{
    const float* x  = (const float*)d_in[0];
    const float* Wq = (const float*)d_in[1];
    const float* bq = (const float*)d_in[2];
    const float* Wk = (const float*)d_in[3];
    const float* bk = (const float*)d_in[4];
    const float* Wv = (const float*)d_in[5];
    const float* bv = (const float*)d_in[6];
    const float* Wo = (const float*)d_in[7];
    const float* bo = (const float*)d_in[8];
    float* out = (float*)d_out;

    const size_t QKV_E = (size_t)MROWS * LQKV;
    const size_t X_E   = (size_t)MROWS * NDIM;
    if (ws_size < (QKV_E + X_E + 4u * 1048576u) * sizeof(bf16_t)) return;

    bf16_t* QKVb = (bf16_t*)d_ws;
    bf16_t* AbX  = QKVb + QKV_E;
    bf16_t* Wc   = AbX + X_E;
    bf16_t* Wob  = Wc + 3u * 1048576u;
    bf16_t* Vtg  = (bf16_t*)d_out;   // 16.8 MB scratch inside the 33.5 MB out buf;
                                     // dead before the O-proj overwrites d_out.

    dim3 blk(256);

    cast_x<<<dim3(4096), blk, 0, stream>>>(x, AbX);
    cast_w<<<dim3(2048), blk, 0, stream>>>(Wq, Wk, Wv, Wo, Wc);

    // fused QKV projection: [8192,1024] x [3072,1024]^T -> [8192,3072]
    gemm_bt<bf16_t><<<dim3(LQKV / 128, MROWS / 128), blk, 0, stream>>>(
        AbX, NDIM, Wc, bq, bk, bv, QKVb, LQKV, NDIM);

    vtrans<<<dim3(SEQ / 64, NBATCH * NHEAD), blk, 0, stream>>>(QKVb, Vtg);

    attn_win<<<dim3(SEQ / 64, NBATCH * NHEAD), blk, 0, stream>>>(QKVb, Vtg, AbX);

    // output projection: [8192,1024] x [1024,1024]^T -> fp32 out
    gemm_bt<float><<<dim3(NDIM / 128, MROWS / 128), blk, 0, stream>>>(
        AbX, NDIM, Wob, bo, bo, bo, out, NDIM, NDIM);
}